// Round 1
// baseline (2298.464 us; speedup 1.0000x reference)
//
#include <hip/hip_runtime.h>
#include <hip/hip_bf16.h>

#define BB 16
#define NN 8192
#define GG 512
#define KK 32
#define DD 128

typedef __attribute__((ext_vector_type(8))) short bf16x8;
typedef __attribute__((ext_vector_type(4))) float f32x4;
typedef __attribute__((ext_vector_type(2))) unsigned int u32x2;
typedef __attribute__((ext_vector_type(4))) unsigned int u32x4;

__device__ __forceinline__ unsigned short f2bf(float f){
  unsigned int u = __builtin_bit_cast(unsigned int, f);
  unsigned int r = (u + 0x7FFFu + ((u >> 16) & 1u)) >> 16;
  return (unsigned short)r;
}
__device__ __forceinline__ float bf2f(unsigned short h){
  unsigned int u = ((unsigned int)h) << 16;
  return __builtin_bit_cast(float, u);
}

// ---------------- FPS: 16 blocks (one per batch) x 1024 threads -------------
__global__ __launch_bounds__(1024)
void fps_kernel(const float* __restrict__ xyz, int* __restrict__ cidx,
                float* __restrict__ center_out, float* __restrict__ cc,
                float* __restrict__ pp)
{
#pragma clang fp contract(off)
  __shared__ float xs[NN], ys[NN], zs[NN];
  __shared__ float redv[16];
  __shared__ int   redi[16];
  __shared__ int   sel_s[GG];
  int b = blockIdx.x, t = threadIdx.x;
  const float* base = xyz + (size_t)b * NN * 3;
  float px[8], py[8], pz[8], dd[8];
#pragma unroll
  for (int i = 0; i < 8; ++i){
    int n = i * 1024 + t;
    float x = base[n*3+0], y = base[n*3+1], z = base[n*3+2];
    xs[n] = x; ys[n] = y; zs[n] = z;
    px[i] = x; py[i] = y; pz[i] = z; dd[i] = 1e10f;
    float sx = x*x, sy = y*y, sz = z*z;
    pp[(size_t)b*NN + n] = (sx + sy) + sz;
  }
  if (t == 0) sel_s[0] = 0;
  __syncthreads();
  float lx = xs[0], ly = ys[0], lz = zs[0];
  for (int g = 1; g < GG; ++g){
    float bv = -1.f; int bi = 0;
#pragma unroll
    for (int i = 0; i < 8; ++i){
      float dx = px[i]-lx, dy = py[i]-ly, dz = pz[i]-lz;
      float sx = dx*dx, sy = dy*dy, sz = dz*dz;
      float d = (sx + sy) + sz;
      float nd = fminf(dd[i], d); dd[i] = nd;
      if (nd > bv){ bv = nd; bi = i*1024 + t; }
    }
#pragma unroll
    for (int m = 1; m < 64; m <<= 1){
      float ov = __shfl_xor(bv, m);
      int   oi = __shfl_xor(bi, m);
      if (ov > bv || (ov == bv && oi < bi)){ bv = ov; bi = oi; }
    }
    if ((t & 63) == 0){ redv[t >> 6] = bv; redi[t >> 6] = bi; }
    __syncthreads();
    bv = redv[0]; bi = redi[0];
#pragma unroll
    for (int wv = 1; wv < 16; ++wv){
      float ov = redv[wv]; int oi = redi[wv];
      if (ov > bv || (ov == bv && oi < bi)){ bv = ov; bi = oi; }
    }
    lx = xs[bi]; ly = ys[bi]; lz = zs[bi];
    if (t == 0) sel_s[g] = bi;
    __syncthreads();
  }
  if (t < GG){
    int n = sel_s[t];
    cidx[b*GG + t] = n;
    float x = xs[n], y = ys[n], z = zs[n];
    center_out[((size_t)b*GG + t)*3 + 0] = x;
    center_out[((size_t)b*GG + t)*3 + 1] = y;
    center_out[((size_t)b*GG + t)*3 + 2] = z;
    float sx = x*x, sy = y*y, sz = z*z;
    cc[b*GG + t] = (sx + sy) + sz;
  }
}

// ---------------- KNN: 8192 blocks (one per b,g) x 256 threads --------------
__global__ __launch_bounds__(256)
void knn_kernel(const float* __restrict__ xyz, const float* __restrict__ center,
                const float* __restrict__ cc, const float* __restrict__ pp,
                int* __restrict__ kidx)
{
#pragma clang fp contract(off)
  __shared__ float d2s[NN];
  __shared__ float redv[4];
  __shared__ int   redi[4];
  int bg = blockIdx.x, t = threadIdx.x;
  int b = bg >> 9;
  const float cx = center[(size_t)bg*3+0];
  const float cy = center[(size_t)bg*3+1];
  const float cz = center[(size_t)bg*3+2];
  const float ccv = cc[bg];
  const float* xb = xyz + (size_t)b*NN*3;
  const float* ppb = pp + (size_t)b*NN;
  float bv = 3.4e38f; int bi = NN;
#pragma unroll 4
  for (int r = 0; r < 32; ++r){
    int n = r*256 + t;
    float x = xb[n*3+0], y = xb[n*3+1], z = xb[n*3+2];
    float dot = (cx*x + cy*y) + cz*z;
    float d = (ccv + ppb[n]) - 2.0f*dot;
    d2s[n] = d;
    if (d < bv || (d == bv && n < bi)){ bv = d; bi = n; }
  }
  __syncthreads();
  for (int k = 0; k < KK; ++k){
    float wv = bv; int wi = bi;
#pragma unroll
    for (int m = 1; m < 64; m <<= 1){
      float ov = __shfl_xor(wv, m); int oi = __shfl_xor(wi, m);
      if (ov < wv || (ov == wv && oi < wi)){ wv = ov; wi = oi; }
    }
    if ((t & 63) == 0){ redv[t >> 6] = wv; redi[t >> 6] = wi; }
    __syncthreads();
    wv = redv[0]; wi = redi[0];
#pragma unroll
    for (int w = 1; w < 4; ++w){
      float ov = redv[w]; int oi = redi[w];
      if (ov < wv || (ov == wv && oi < wi)){ wv = ov; wi = oi; }
    }
    if (t == (wi & 255)){
      d2s[wi] = 3.4e38f;
      bv = 3.4e38f; bi = NN;
      for (int r = 0; r < 32; ++r){
        int n = r*256 + t;
        float v = d2s[n];
        if (v < bv || (v == bv && n < bi)){ bv = v; bi = n; }
      }
    }
    if (t == 0) kidx[(size_t)bg*KK + k] = wi;
    __syncthreads();
  }
}

// ---------------- W -> bf16 prep -------------------------------------------
__global__ __launch_bounds__(256)
void wprep_kernel(const float* __restrict__ W1, const float* __restrict__ W2,
                  const float* __restrict__ W3, unsigned short* __restrict__ Wbf)
{
  int i = blockIdx.x * 256 + threadIdx.x;  // 65536 total
  float v;
  if (i < 16384)      v = W1[i];
  else if (i < 32768) v = W2[i - 16384];
  else                v = W3[i - 32768];
  Wbf[i] = f2bf(v);
}

// ---------------- fused GEMM/BN-stat/store/pool -----------------------------
// Y[o, j] = W[o,c] X[c,j] + bias[o], j = (b*G+g)*K + k, tile: 64 j per block.
// MODE 0: X gathered from points via knn idx (f32 -> bf16)
// MODE 1: X = relu(Yprev * sc_in + sh_in) from bf16 Yprev
template<int OC, int MODE, bool STATS, bool STORE, bool POOL>
__global__ __launch_bounds__(256)
void gemm_kernel(const unsigned short* __restrict__ Wbf, const float* __restrict__ bias,
                 const float* __restrict__ points, const int* __restrict__ kidx,
                 const unsigned short* __restrict__ Xin,
                 const float* __restrict__ sc_in, const float* __restrict__ sh_in,
                 unsigned short* __restrict__ Yout, float* __restrict__ psum,
                 const float* __restrict__ sc_out, const float* __restrict__ sh_out,
                 float* __restrict__ opool)
{
  constexpr int MF = OC / 64;             // 16-row m-frags per wave
  __shared__ unsigned short smem[64 * OC]; // X tile (first 64*128) / Y epilogue
  __shared__ float ssc[128], ssh[128];
  int t = threadIdx.x;
  int l = t & 63, w = t >> 6;
  int l15 = l & 15, lh = l >> 4;
  int jbase = blockIdx.x * 64;
  int obase = w * (OC / 4);

  if constexpr (MODE == 1){
    if (t < 128){ ssc[t] = sc_in[t]; ssh[t] = sh_in[t]; }
  }

  // A fragments (W) straight from global (L1/L2-hot)
  bf16x8 a[MF][4];
#pragma unroll
  for (int m = 0; m < MF; ++m)
#pragma unroll
    for (int kf = 0; kf < 4; ++kf){
      int row = obase + m*16 + l15;
      int c8  = kf*32 + lh*8;
      a[m][kf] = *(const bf16x8*)(Wbf + (size_t)row*128 + c8);
    }

  if constexpr (MODE == 1) __syncthreads();

  // stage X tile [64 j][128 c] bf16, chunk-XOR swizzled
#pragma unroll
  for (int q = 0; q < 4; ++q){
    int ci = q*256 + t;
    int j = ci >> 4, cc = ci & 15;
    unsigned short* dst = &smem[j*128 + ((cc ^ (j & 15)) * 8)];
    if constexpr (MODE == 0){
      int jg = jbase + j;
      int bb = jg >> 14;                 // / (G*K)
      int row = kidx[jg];
      const float* src = points + ((size_t)bb*NN + row)*DD + cc*8;
      f32x4 u0 = *(const f32x4*)src;
      f32x4 u1 = *(const f32x4*)(src + 4);
      unsigned int w0 = f2bf(u0[0]) | ((unsigned int)f2bf(u0[1]) << 16);
      unsigned int w1 = f2bf(u0[2]) | ((unsigned int)f2bf(u0[3]) << 16);
      unsigned int w2 = f2bf(u1[0]) | ((unsigned int)f2bf(u1[1]) << 16);
      unsigned int w3 = f2bf(u1[2]) | ((unsigned int)f2bf(u1[3]) << 16);
      u32x4 pv = {w0, w1, w2, w3};
      *(u32x4*)dst = pv;
    } else {
      const unsigned short* src = Xin + ((size_t)(jbase + j))*128 + cc*8;
      u32x4 v = *(const u32x4*)src;
      int c0 = cc * 8;
      unsigned int wo[4];
#pragma unroll
      for (int p = 0; p < 4; ++p){
        float x0 = bf2f((unsigned short)(v[p] & 0xFFFFu));
        float x1 = bf2f((unsigned short)(v[p] >> 16));
        x0 = fmaxf(fmaf(x0, ssc[c0 + 2*p],     ssh[c0 + 2*p]),     0.f);
        x1 = fmaxf(fmaf(x1, ssc[c0 + 2*p + 1], ssh[c0 + 2*p + 1]), 0.f);
        wo[p] = f2bf(x0) | ((unsigned int)f2bf(x1) << 16);
      }
      u32x4 pv = {wo[0], wo[1], wo[2], wo[3]};
      *(u32x4*)dst = pv;
    }
  }
  __syncthreads();

  f32x4 acc[MF][4];
#pragma unroll
  for (int m = 0; m < MF; ++m)
#pragma unroll
    for (int n = 0; n < 4; ++n)
      acc[m][n] = (f32x4){0.f, 0.f, 0.f, 0.f};

#pragma unroll
  for (int n = 0; n < 4; ++n){
    bf16x8 bfr[4];
    int j = n*16 + l15;
#pragma unroll
    for (int kf = 0; kf < 4; ++kf){
      int ch = kf*4 + lh;
      bfr[kf] = *(const bf16x8*)&smem[j*128 + ((ch ^ (j & 15)) * 8)];
    }
#pragma unroll
    for (int m = 0; m < MF; ++m)
#pragma unroll
      for (int kf = 0; kf < 4; ++kf)
        acc[m][n] = __builtin_amdgcn_mfma_f32_16x16x32_bf16(a[m][kf], bfr[kf], acc[m][n], 0, 0, 0);
  }

  // + bias
#pragma unroll
  for (int m = 0; m < MF; ++m){
    int o0 = obase + m*16 + lh*4;
    f32x4 bv = *(const f32x4*)(bias + o0);
#pragma unroll
    for (int n = 0; n < 4; ++n) acc[m][n] += bv;
  }

  if constexpr (STATS){
    int slot = blockIdx.x & 63;
#pragma unroll
    for (int m = 0; m < MF; ++m){
#pragma unroll
      for (int r = 0; r < 4; ++r){
        float s = 0.f, q2 = 0.f;
#pragma unroll
        for (int n = 0; n < 4; ++n){ float v = acc[m][n][r]; s += v; q2 += v*v; }
        s  += __shfl_xor(s, 1);  s  += __shfl_xor(s, 2);  s  += __shfl_xor(s, 4);  s  += __shfl_xor(s, 8);
        q2 += __shfl_xor(q2, 1); q2 += __shfl_xor(q2, 2); q2 += __shfl_xor(q2, 4); q2 += __shfl_xor(q2, 8);
        if (l15 == 0){
          int o = obase + m*16 + lh*4 + r;
          atomicAdd(psum + slot*OC + o, s);
          atomicAdd(psum + 64*OC + slot*OC + o, q2);
        }
      }
    }
  }

  if constexpr (POOL){
#pragma unroll
    for (int m = 0; m < MF; ++m){
      int o0 = obase + m*16 + lh*4;
      f32x4 sc = *(const f32x4*)(sc_out + o0);
      f32x4 sh = *(const f32x4*)(sh_out + o0);
      f32x4 g0, g1;
#pragma unroll
      for (int r = 0; r < 4; ++r){
        float v0 = fmaxf(fmaf(acc[m][0][r], sc[r], sh[r]), 0.f);
        float v1 = fmaxf(fmaf(acc[m][1][r], sc[r], sh[r]), 0.f);
        float v2 = fmaxf(fmaf(acc[m][2][r], sc[r], sh[r]), 0.f);
        float v3 = fmaxf(fmaf(acc[m][3][r], sc[r], sh[r]), 0.f);
        float a0 = fmaxf(v0, v1), a1 = fmaxf(v2, v3);
#pragma unroll
        for (int mk = 1; mk < 16; mk <<= 1){
          a0 = fmaxf(a0, __shfl_xor(a0, mk));
          a1 = fmaxf(a1, __shfl_xor(a1, mk));
        }
        g0[r] = a0; g1[r] = a1;
      }
      if (l15 == 0){
        int gg = jbase >> 5;               // group index (2 per tile)
        *(f32x4*)(opool + (size_t)gg*256 + o0)       = g0;
        *(f32x4*)(opool + (size_t)(gg + 1)*256 + o0) = g1;
      }
    }
  }

  if constexpr (STORE){
    __syncthreads();
#pragma unroll
    for (int m = 0; m < MF; ++m){
      int o0 = obase + m*16 + lh*4;
      int co = o0 >> 2;
#pragma unroll
      for (int n = 0; n < 4; ++n){
        int j = n*16 + l15;
        unsigned int w0 = f2bf(acc[m][n][0]) | ((unsigned int)f2bf(acc[m][n][1]) << 16);
        unsigned int w1 = f2bf(acc[m][n][2]) | ((unsigned int)f2bf(acc[m][n][3]) << 16);
        u32x2 pv = {w0, w1};
        *(u32x2*)&smem[j*OC + ((co ^ ((j & 15) << 1)) * 4)] = pv;
      }
    }
    __syncthreads();
    constexpr int CPR = OC / 4;            // 8B chunks per row
    constexpr int CPT = (64 * CPR) / 256;  // per thread
#pragma unroll
    for (int q = 0; q < CPT; ++q){
      int ci = q*256 + t;
      int j = ci / CPR, co = ci % CPR;
      u32x2 v = *(const u32x2*)&smem[j*OC + ((co ^ ((j & 15) << 1)) * 4)];
      *(u32x2*)(Yout + (size_t)(jbase + j)*OC + co*4) = v;
    }
  }
}

// ---------------- BN scale/shift from partials ------------------------------
__global__ __launch_bounds__(256)
void bnprep_kernel(const float* __restrict__ psum, int OC,
                   const float* __restrict__ g, const float* __restrict__ be,
                   float* __restrict__ scale, float* __restrict__ shift)
{
  int t = threadIdx.x;
  if (t >= OC) return;
  float s = 0.f, q = 0.f;
  for (int slot = 0; slot < 64; ++slot){
    s += psum[slot*OC + t];
    q += psum[64*OC + slot*OC + t];
  }
  const float inv = 1.f / 262144.f;        // B*K*G
  float mean = s * inv;
  float var  = q * inv - mean*mean;
  float sc = g[t] * rsqrtf(var + 1e-5f);
  scale[t] = sc;
  shift[t] = be[t] - mean*sc;
}

// ---------------- launch ----------------------------------------------------
extern "C" void kernel_launch(void* const* d_in, const int* in_sizes, int n_in,
                              void* d_out, int out_size, void* d_ws, size_t ws_size,
                              hipStream_t stream)
{
  const float* xyz    = (const float*)d_in[0];
  const float* points = (const float*)d_in[1];
  const float* W1  = (const float*)d_in[2];
  const float* b1  = (const float*)d_in[3];
  const float* g1  = (const float*)d_in[4];
  const float* be1 = (const float*)d_in[5];
  const float* W2  = (const float*)d_in[6];
  const float* b2  = (const float*)d_in[7];
  const float* g2  = (const float*)d_in[8];
  const float* be2 = (const float*)d_in[9];
  const float* W3  = (const float*)d_in[10];
  const float* b3  = (const float*)d_in[11];
  const float* g3  = (const float*)d_in[12];
  const float* be3 = (const float*)d_in[13];

  float* out    = (float*)d_out;
  float* center = out;                      // [B,G,3]
  float* opool  = out + (size_t)BB*GG*3;    // [B,G,256]

  char* ws = (char*)d_ws;
  size_t off = 0;
  auto alloc = [&](size_t bytes) -> void* {
    void* p = ws + off;
    off += (bytes + 255) & ~(size_t)255;
    return p;
  };
  unsigned short* Y1   = (unsigned short*)alloc((size_t)262144*128*2);
  unsigned short* Y2   = (unsigned short*)alloc((size_t)262144*128*2);
  int*   kidx = (int*)  alloc((size_t)262144*4);
  int*   cidx = (int*)  alloc((size_t)8192*4);
  float* ccb  = (float*)alloc((size_t)8192*4);
  float* ppb  = (float*)alloc((size_t)131072*4);
  unsigned short* Wbf = (unsigned short*)alloc((size_t)65536*2);
  float* sc1 = (float*)alloc(256*4);
  float* sh1 = (float*)alloc(256*4);
  float* sc2 = (float*)alloc(256*4);
  float* sh2 = (float*)alloc(256*4);
  float* sc3 = (float*)alloc(256*4);
  float* sh3 = (float*)alloc(256*4);
  float* psumA = (float*)alloc((size_t)2*64*128*4);
  float* psumB = (float*)alloc((size_t)2*64*128*4);
  float* psumC = (float*)alloc((size_t)2*64*256*4);

  // zero the BN partial accumulators (contiguous allocations)
  hipMemsetAsync(psumA, 0, (size_t)(2*64*128 + 2*64*128 + 2*64*256)*4 + 1024, stream);

  fps_kernel<<<BB, 1024, 0, stream>>>(xyz, cidx, center, ccb, ppb);
  knn_kernel<<<BB*GG, 256, 0, stream>>>(xyz, center, ccb, ppb, kidx);
  wprep_kernel<<<256, 256, 0, stream>>>(W1, W2, W3, Wbf);

  // layer 1: gather + GEMM + stats + store
  gemm_kernel<128, 0, true, true, false><<<4096, 256, 0, stream>>>(
      Wbf, b1, points, kidx, nullptr, nullptr, nullptr, Y1, psumA,
      nullptr, nullptr, nullptr);
  bnprep_kernel<<<1, 256, 0, stream>>>(psumA, 128, g1, be1, sc1, sh1);

  // layer 2
  gemm_kernel<128, 1, true, true, false><<<4096, 256, 0, stream>>>(
      Wbf + 16384, b2, nullptr, nullptr, Y1, sc1, sh1, Y2, psumB,
      nullptr, nullptr, nullptr);
  bnprep_kernel<<<1, 256, 0, stream>>>(psumB, 128, g2, be2, sc2, sh2);

  // layer 3 pass 1: stats only
  gemm_kernel<256, 1, true, false, false><<<4096, 256, 0, stream>>>(
      Wbf + 32768, b3, nullptr, nullptr, Y2, sc2, sh2, nullptr, psumC,
      nullptr, nullptr, nullptr);
  bnprep_kernel<<<1, 256, 0, stream>>>(psumC, 256, g3, be3, sc3, sh3);

  // layer 3 pass 2: recompute + BN + relu + maxpool -> d_out
  gemm_kernel<256, 1, false, false, true><<<4096, 256, 0, stream>>>(
      Wbf + 32768, b3, nullptr, nullptr, Y2, sc2, sh2, nullptr, nullptr,
      sc3, sh3, opool);
}

// Round 2
// 1151.035 us; speedup vs baseline: 1.9969x; 1.9969x over previous
//
#include <hip/hip_runtime.h>
#include <hip/hip_bf16.h>

#define BB 16
#define NN 8192
#define GG 512
#define KK 32
#define DD 128

typedef __attribute__((ext_vector_type(8))) short bf16x8;
typedef __attribute__((ext_vector_type(4))) float f32x4;
typedef __attribute__((ext_vector_type(2))) float f32x2;
typedef __attribute__((ext_vector_type(2))) unsigned int u32x2;
typedef __attribute__((ext_vector_type(4))) unsigned int u32x4;

__device__ __forceinline__ unsigned short f2bf(float f){
  unsigned int u = __builtin_bit_cast(unsigned int, f);
  unsigned int r = (u + 0x7FFFu + ((u >> 16) & 1u)) >> 16;
  return (unsigned short)r;
}
__device__ __forceinline__ float bf2f(unsigned short h){
  unsigned int u = ((unsigned int)h) << 16;
  return __builtin_bit_cast(float, u);
}

// DPP wave64 reductions: row_shr 1/2/4/8 then row_bcast15/31; result in lane 63.
__device__ __forceinline__ float wave_max_f32(float v){
  int x = __builtin_bit_cast(int, v);
#define STEPMAX(C) { int y = __builtin_amdgcn_update_dpp(x, x, C, 0xF, 0xF, false); \
  float f = fmaxf(__builtin_bit_cast(float,x), __builtin_bit_cast(float,y)); x = __builtin_bit_cast(int,f); }
  STEPMAX(0x111) STEPMAX(0x112) STEPMAX(0x114) STEPMAX(0x118) STEPMAX(0x142) STEPMAX(0x143)
#undef STEPMAX
  return __builtin_bit_cast(float, __builtin_amdgcn_readlane(x, 63));
}
__device__ __forceinline__ float wave_min_f32(float v){
  int x = __builtin_bit_cast(int, v);
#define STEPMIN(C) { int y = __builtin_amdgcn_update_dpp(x, x, C, 0xF, 0xF, false); \
  float f = fminf(__builtin_bit_cast(float,x), __builtin_bit_cast(float,y)); x = __builtin_bit_cast(int,f); }
  STEPMIN(0x111) STEPMIN(0x112) STEPMIN(0x114) STEPMIN(0x118) STEPMIN(0x142) STEPMIN(0x143)
#undef STEPMIN
  return __builtin_bit_cast(float, __builtin_amdgcn_readlane(x, 63));
}

// ---------------- FPS: 16 blocks (one per batch) x 1024 threads -------------
__global__ __launch_bounds__(1024)
void fps_kernel(const float* __restrict__ xyz,
                float* __restrict__ center_out, float* __restrict__ cc,
                float* __restrict__ pp)
{
#pragma clang fp contract(off)
  __shared__ float xs[NN], ys[NN], zs[NN];
  __shared__ float redv[16];
  __shared__ int   sel2[2];
  __shared__ int   sel_s[GG];
  int b = blockIdx.x, t = threadIdx.x;
  int lane = t & 63, wid = t >> 6;
  const float* base = xyz + (size_t)b * NN * 3;
  f32x2 px[4], py[4], pz[4], dd[4];
#pragma unroll
  for (int i = 0; i < 4; ++i){
    int n0 = (2*i) * 1024 + t, n1 = n0 + 1024;
    float x0 = base[n0*3+0], y0 = base[n0*3+1], z0 = base[n0*3+2];
    float x1 = base[n1*3+0], y1 = base[n1*3+1], z1 = base[n1*3+2];
    xs[n0] = x0; ys[n0] = y0; zs[n0] = z0;
    xs[n1] = x1; ys[n1] = y1; zs[n1] = z1;
    px[i] = (f32x2){x0, x1}; py[i] = (f32x2){y0, y1}; pz[i] = (f32x2){z0, z1};
    dd[i] = (f32x2){1e10f, 1e10f};
    pp[(size_t)b*NN + n0] = (x0*x0 + y0*y0) + z0*z0;
    pp[(size_t)b*NN + n1] = (x1*x1 + y1*y1) + z1*z1;
  }
  if (t < 2)  sel2[t] = 0x7FFFFFFF;
  if (t == 0) sel_s[0] = 0;
  __syncthreads();
  float lx = xs[0], ly = ys[0], lz = zs[0];
  for (int g = 1; g < GG; ++g){
    f32x2 lxv = (f32x2){lx, lx}, lyv = (f32x2){ly, ly}, lzv = (f32x2){lz, lz};
    f32x2 vm = (f32x2){-1.f, -1.f};
#pragma unroll
    for (int i = 0; i < 4; ++i){
      f32x2 dx = px[i] - lxv, dy = py[i] - lyv, dz = pz[i] - lzv;
      f32x2 s = (dx*dx + dy*dy) + dz*dz;
      dd[i] = __builtin_elementwise_min(dd[i], s);
      vm = __builtin_elementwise_max(vm, dd[i]);
    }
    float wmax = wave_max_f32(fmaxf(vm.x, vm.y));
    if (lane == 0) redv[wid] = wmax;
    __syncthreads();                       // A
    if (t == 0) sel2[(g + 1) & 1] = 0x7FFFFFFF;   // reset other slot (safe: last read pre-A)
    float bmax;
    {
      f32x4 r0 = *(f32x4*)&redv[0],  r1 = *(f32x4*)&redv[4];
      f32x4 r2 = *(f32x4*)&redv[8],  r3 = *(f32x4*)&redv[12];
      f32x4 m = __builtin_elementwise_max(__builtin_elementwise_max(r0, r1),
                                          __builtin_elementwise_max(r2, r3));
      bmax = fmaxf(fmaxf(m[0], m[1]), fmaxf(m[2], m[3]));
    }
    int cand = 0x7FFFFFFF;
#pragma unroll
    for (int i = 0; i < 4; ++i){
      int n0 = (2*i) * 1024 + t;
      if (dd[i].x == bmax) cand = min(cand, n0);
      if (dd[i].y == bmax) cand = min(cand, n0 + 1024);
    }
    if (cand != 0x7FFFFFFF) atomicMin(&sel2[g & 1], cand);
    __syncthreads();                       // B
    int bi = sel2[g & 1];
    lx = xs[bi]; ly = ys[bi]; lz = zs[bi];
    if (t == 0) sel_s[g] = bi;
  }
  __syncthreads();
  if (t < GG){
    int n = sel_s[t];
    float x = xs[n], y = ys[n], z = zs[n];
    center_out[((size_t)b*GG + t)*3 + 0] = x;
    center_out[((size_t)b*GG + t)*3 + 1] = y;
    center_out[((size_t)b*GG + t)*3 + 2] = z;
    cc[b*GG + t] = (x*x + y*y) + z*z;
  }
}

// ---------------- KNN: 8192 blocks (one per b,g) x 256 threads --------------
// Per-thread stripe of 32 distances lives in REGISTERS (private), DPP reduce.
__global__ __launch_bounds__(256)
void knn_kernel(const float* __restrict__ xyz, const float* __restrict__ center,
                const float* __restrict__ cc, const float* __restrict__ pp,
                int* __restrict__ kidx)
{
#pragma clang fp contract(off)
  __shared__ float redvk[4];
  __shared__ int   selk[2];
  int bg = blockIdx.x, t = threadIdx.x;
  int lane = t & 63, w = t >> 6;
  int b = bg >> 9;
  const float cx = center[(size_t)bg*3+0];
  const float cy = center[(size_t)bg*3+1];
  const float cz = center[(size_t)bg*3+2];
  const float ccv = cc[bg];
  const float* xb  = xyz + (size_t)b*NN*3;
  const float* ppb = pp  + (size_t)b*NN;
  float d2r[32];
  float bv = 3.4e38f; int bi = 0x7FFFFFFF;
#pragma unroll
  for (int r = 0; r < 32; ++r){
    int n = r*256 + t;
    float x = xb[n*3+0], y = xb[n*3+1], z = xb[n*3+2];
    float dot = (cx*x + cy*y) + cz*z;
    float d = (ccv + ppb[n]) - 2.0f*dot;
    d2r[r] = d;
    if (d < bv){ bv = d; bi = n; }       // ascending n: strict < keeps lowest idx
  }
  if (t < 2) selk[t] = 0x7FFFFFFF;
  for (int k = 0; k < KK; ++k){
    float wmin = wave_min_f32(bv);
    if (lane == 0) redvk[w] = wmin;
    __syncthreads();                     // A (also orders selk init/reset)
    if (t == 0) selk[(k + 1) & 1] = 0x7FFFFFFF;
    float bmin = fminf(fminf(redvk[0], redvk[1]), fminf(redvk[2], redvk[3]));
    if (bv == bmin) atomicMin(&selk[k & 1], bi);
    __syncthreads();                     // B
    int wi = selk[k & 1];
    if (t == 0) kidx[(size_t)bg*KK + k] = wi;
    if (wi == bi){                       // winner: invalidate + register rescan
      bv = 3.4e38f; bi = 0x7FFFFFFF;
#pragma unroll
      for (int r = 0; r < 32; ++r){
        int n = r*256 + t;
        float v = (n == wi) ? 3.4e38f : d2r[r];
        d2r[r] = v;
        if (v < bv){ bv = v; bi = n; }
      }
    }
  }
}

// ---------------- W -> bf16 prep -------------------------------------------
__global__ __launch_bounds__(256)
void wprep_kernel(const float* __restrict__ W1, const float* __restrict__ W2,
                  const float* __restrict__ W3, unsigned short* __restrict__ Wbf)
{
  int i = blockIdx.x * 256 + threadIdx.x;  // 65536 total
  float v;
  if (i < 16384)      v = W1[i];
  else if (i < 32768) v = W2[i - 16384];
  else                v = W3[i - 32768];
  Wbf[i] = f2bf(v);
}

// ---------------- fused GEMM/BN-stat/store/pool -----------------------------
template<int OC, int MODE, bool STATS, bool STORE, bool POOL>
__global__ __launch_bounds__(256)
void gemm_kernel(const unsigned short* __restrict__ Wbf, const float* __restrict__ bias,
                 const float* __restrict__ points, const int* __restrict__ kidx,
                 const unsigned short* __restrict__ Xin,
                 const float* __restrict__ sc_in, const float* __restrict__ sh_in,
                 unsigned short* __restrict__ Yout, float* __restrict__ psum,
                 const float* __restrict__ sc_out, const float* __restrict__ sh_out,
                 float* __restrict__ opool)
{
  constexpr int MF = OC / 64;             // 16-row m-frags per wave
  __shared__ unsigned short smem[64 * OC]; // X tile (first 64*128) / Y epilogue
  __shared__ float ssc[128], ssh[128];
  int t = threadIdx.x;
  int l = t & 63, w = t >> 6;
  int l15 = l & 15, lh = l >> 4;
  int jbase = blockIdx.x * 64;
  int obase = w * (OC / 4);

  if constexpr (MODE == 1){
    if (t < 128){ ssc[t] = sc_in[t]; ssh[t] = sh_in[t]; }
  }

  bf16x8 a[MF][4];
#pragma unroll
  for (int m = 0; m < MF; ++m)
#pragma unroll
    for (int kf = 0; kf < 4; ++kf){
      int row = obase + m*16 + l15;
      int c8  = kf*32 + lh*8;
      a[m][kf] = *(const bf16x8*)(Wbf + (size_t)row*128 + c8);
    }

  if constexpr (MODE == 1) __syncthreads();

#pragma unroll
  for (int q = 0; q < 4; ++q){
    int ci = q*256 + t;
    int j = ci >> 4, cc = ci & 15;
    unsigned short* dst = &smem[j*128 + ((cc ^ (j & 15)) * 8)];
    if constexpr (MODE == 0){
      int jg = jbase + j;
      int bb = jg >> 14;                 // / (G*K)
      int row = kidx[jg];
      const float* src = points + ((size_t)bb*NN + row)*DD + cc*8;
      f32x4 u0 = *(const f32x4*)src;
      f32x4 u1 = *(const f32x4*)(src + 4);
      unsigned int w0 = f2bf(u0[0]) | ((unsigned int)f2bf(u0[1]) << 16);
      unsigned int w1 = f2bf(u0[2]) | ((unsigned int)f2bf(u0[3]) << 16);
      unsigned int w2 = f2bf(u1[0]) | ((unsigned int)f2bf(u1[1]) << 16);
      unsigned int w3 = f2bf(u1[2]) | ((unsigned int)f2bf(u1[3]) << 16);
      u32x4 pv = {w0, w1, w2, w3};
      *(u32x4*)dst = pv;
    } else {
      const unsigned short* src = Xin + ((size_t)(jbase + j))*128 + cc*8;
      u32x4 v = *(const u32x4*)src;
      int c0 = cc * 8;
      unsigned int wo[4];
#pragma unroll
      for (int p = 0; p < 4; ++p){
        float x0 = bf2f((unsigned short)(v[p] & 0xFFFFu));
        float x1 = bf2f((unsigned short)(v[p] >> 16));
        x0 = fmaxf(fmaf(x0, ssc[c0 + 2*p],     ssh[c0 + 2*p]),     0.f);
        x1 = fmaxf(fmaf(x1, ssc[c0 + 2*p + 1], ssh[c0 + 2*p + 1]), 0.f);
        wo[p] = f2bf(x0) | ((unsigned int)f2bf(x1) << 16);
      }
      u32x4 pv = {wo[0], wo[1], wo[2], wo[3]};
      *(u32x4*)dst = pv;
    }
  }
  __syncthreads();

  f32x4 acc[MF][4];
#pragma unroll
  for (int m = 0; m < MF; ++m)
#pragma unroll
    for (int n = 0; n < 4; ++n)
      acc[m][n] = (f32x4){0.f, 0.f, 0.f, 0.f};

#pragma unroll
  for (int n = 0; n < 4; ++n){
    bf16x8 bfr[4];
    int j = n*16 + l15;
#pragma unroll
    for (int kf = 0; kf < 4; ++kf){
      int ch = kf*4 + lh;
      bfr[kf] = *(const bf16x8*)&smem[j*128 + ((ch ^ (j & 15)) * 8)];
    }
#pragma unroll
    for (int m = 0; m < MF; ++m)
#pragma unroll
      for (int kf = 0; kf < 4; ++kf)
        acc[m][n] = __builtin_amdgcn_mfma_f32_16x16x32_bf16(a[m][kf], bfr[kf], acc[m][n], 0, 0, 0);
  }

#pragma unroll
  for (int m = 0; m < MF; ++m){
    int o0 = obase + m*16 + lh*4;
    f32x4 bv = *(const f32x4*)(bias + o0);
#pragma unroll
    for (int n = 0; n < 4; ++n) acc[m][n] += bv;
  }

  if constexpr (STATS){
    int slot = blockIdx.x & 63;
#pragma unroll
    for (int m = 0; m < MF; ++m){
#pragma unroll
      for (int r = 0; r < 4; ++r){
        float s = 0.f, q2 = 0.f;
#pragma unroll
        for (int n = 0; n < 4; ++n){ float v = acc[m][n][r]; s += v; q2 += v*v; }
        s  += __shfl_xor(s, 1);  s  += __shfl_xor(s, 2);  s  += __shfl_xor(s, 4);  s  += __shfl_xor(s, 8);
        q2 += __shfl_xor(q2, 1); q2 += __shfl_xor(q2, 2); q2 += __shfl_xor(q2, 4); q2 += __shfl_xor(q2, 8);
        if (l15 == 0){
          int o = obase + m*16 + lh*4 + r;
          atomicAdd(psum + slot*OC + o, s);
          atomicAdd(psum + 64*OC + slot*OC + o, q2);
        }
      }
    }
  }

  if constexpr (POOL){
#pragma unroll
    for (int m = 0; m < MF; ++m){
      int o0 = obase + m*16 + lh*4;
      f32x4 sc = *(const f32x4*)(sc_out + o0);
      f32x4 sh = *(const f32x4*)(sh_out + o0);
      f32x4 g0, g1;
#pragma unroll
      for (int r = 0; r < 4; ++r){
        float v0 = fmaxf(fmaf(acc[m][0][r], sc[r], sh[r]), 0.f);
        float v1 = fmaxf(fmaf(acc[m][1][r], sc[r], sh[r]), 0.f);
        float v2 = fmaxf(fmaf(acc[m][2][r], sc[r], sh[r]), 0.f);
        float v3 = fmaxf(fmaf(acc[m][3][r], sc[r], sh[r]), 0.f);
        float a0 = fmaxf(v0, v1), a1 = fmaxf(v2, v3);
#pragma unroll
        for (int mk = 1; mk < 16; mk <<= 1){
          a0 = fmaxf(a0, __shfl_xor(a0, mk));
          a1 = fmaxf(a1, __shfl_xor(a1, mk));
        }
        g0[r] = a0; g1[r] = a1;
      }
      if (l15 == 0){
        int gg = jbase >> 5;
        *(f32x4*)(opool + (size_t)gg*256 + o0)       = g0;
        *(f32x4*)(opool + (size_t)(gg + 1)*256 + o0) = g1;
      }
    }
  }

  if constexpr (STORE){
    __syncthreads();
#pragma unroll
    for (int m = 0; m < MF; ++m){
      int o0 = obase + m*16 + lh*4;
      int co = o0 >> 2;
#pragma unroll
      for (int n = 0; n < 4; ++n){
        int j = n*16 + l15;
        unsigned int w0 = f2bf(acc[m][n][0]) | ((unsigned int)f2bf(acc[m][n][1]) << 16);
        unsigned int w1 = f2bf(acc[m][n][2]) | ((unsigned int)f2bf(acc[m][n][3]) << 16);
        u32x2 pv = {w0, w1};
        *(u32x2*)&smem[j*OC + ((co ^ ((j & 15) << 1)) * 4)] = pv;
      }
    }
    __syncthreads();
    constexpr int CPR = OC / 4;
    constexpr int CPT = (64 * CPR) / 256;
#pragma unroll
    for (int q = 0; q < CPT; ++q){
      int ci = q*256 + t;
      int j = ci / CPR, co = ci % CPR;
      u32x2 v = *(const u32x2*)&smem[j*OC + ((co ^ ((j & 15) << 1)) * 4)];
      *(u32x2*)(Yout + (size_t)(jbase + j)*OC + co*4) = v;
    }
  }
}

// ---------------- BN scale/shift from partials ------------------------------
__global__ __launch_bounds__(256)
void bnprep_kernel(const float* __restrict__ psum, int OC,
                   const float* __restrict__ g, const float* __restrict__ be,
                   float* __restrict__ scale, float* __restrict__ shift)
{
  int t = threadIdx.x;
  if (t >= OC) return;
  float s = 0.f, q = 0.f;
  for (int slot = 0; slot < 64; ++slot){
    s += psum[slot*OC + t];
    q += psum[64*OC + slot*OC + t];
  }
  const float inv = 1.f / 262144.f;        // B*K*G
  float mean = s * inv;
  float var  = q * inv - mean*mean;
  float sc = g[t] * rsqrtf(var + 1e-5f);
  scale[t] = sc;
  shift[t] = be[t] - mean*sc;
}

// ---------------- launch ----------------------------------------------------
extern "C" void kernel_launch(void* const* d_in, const int* in_sizes, int n_in,
                              void* d_out, int out_size, void* d_ws, size_t ws_size,
                              hipStream_t stream)
{
  const float* xyz    = (const float*)d_in[0];
  const float* points = (const float*)d_in[1];
  const float* W1  = (const float*)d_in[2];
  const float* b1  = (const float*)d_in[3];
  const float* g1  = (const float*)d_in[4];
  const float* be1 = (const float*)d_in[5];
  const float* W2  = (const float*)d_in[6];
  const float* b2  = (const float*)d_in[7];
  const float* g2  = (const float*)d_in[8];
  const float* be2 = (const float*)d_in[9];
  const float* W3  = (const float*)d_in[10];
  const float* b3  = (const float*)d_in[11];
  const float* g3  = (const float*)d_in[12];
  const float* be3 = (const float*)d_in[13];

  float* out    = (float*)d_out;
  float* center = out;                      // [B,G,3]
  float* opool  = out + (size_t)BB*GG*3;    // [B,G,256]

  char* ws = (char*)d_ws;
  size_t off = 0;
  auto alloc = [&](size_t bytes) -> void* {
    void* p = ws + off;
    off += (bytes + 255) & ~(size_t)255;
    return p;
  };
  unsigned short* Y1   = (unsigned short*)alloc((size_t)262144*128*2);
  unsigned short* Y2   = (unsigned short*)alloc((size_t)262144*128*2);
  int*   kidx = (int*)  alloc((size_t)262144*4);
  float* ccb  = (float*)alloc((size_t)8192*4);
  float* ppb  = (float*)alloc((size_t)131072*4);
  unsigned short* Wbf = (unsigned short*)alloc((size_t)65536*2);
  float* sc1 = (float*)alloc(256*4);
  float* sh1 = (float*)alloc(256*4);
  float* sc2 = (float*)alloc(256*4);
  float* sh2 = (float*)alloc(256*4);
  float* sc3 = (float*)alloc(256*4);
  float* sh3 = (float*)alloc(256*4);
  float* psumA = (float*)alloc((size_t)2*64*128*4);
  float* psumB = (float*)alloc((size_t)2*64*128*4);
  float* psumC = (float*)alloc((size_t)2*64*256*4);

  hipMemsetAsync(psumA, 0, (size_t)(2*64*128 + 2*64*128 + 2*64*256)*4 + 1024, stream);

  fps_kernel<<<BB, 1024, 0, stream>>>(xyz, center, ccb, ppb);
  knn_kernel<<<BB*GG, 256, 0, stream>>>(xyz, center, ccb, ppb, kidx);
  wprep_kernel<<<256, 256, 0, stream>>>(W1, W2, W3, Wbf);

  gemm_kernel<128, 0, true, true, false><<<4096, 256, 0, stream>>>(
      Wbf, b1, points, kidx, nullptr, nullptr, nullptr, Y1, psumA,
      nullptr, nullptr, nullptr);
  bnprep_kernel<<<1, 256, 0, stream>>>(psumA, 128, g1, be1, sc1, sh1);

  gemm_kernel<128, 1, true, true, false><<<4096, 256, 0, stream>>>(
      Wbf + 16384, b2, nullptr, nullptr, Y1, sc1, sh1, Y2, psumB,
      nullptr, nullptr, nullptr);
  bnprep_kernel<<<1, 256, 0, stream>>>(psumB, 128, g2, be2, sc2, sh2);

  gemm_kernel<256, 1, true, false, false><<<4096, 256, 0, stream>>>(
      Wbf + 32768, b3, nullptr, nullptr, Y2, sc2, sh2, nullptr, psumC,
      nullptr, nullptr, nullptr);
  bnprep_kernel<<<1, 256, 0, stream>>>(psumC, 256, g3, be3, sc3, sh3);

  gemm_kernel<256, 1, false, false, true><<<4096, 256, 0, stream>>>(
      Wbf + 32768, b3, nullptr, nullptr, Y2, sc2, sh2, nullptr, nullptr,
      sc3, sh3, opool);
}